// Round 2
// baseline (406.769 us; speedup 1.0000x reference)
//
#include <hip/hip_runtime.h>
#include <stdint.h>

typedef __bf16 bf16x8 __attribute__((ext_vector_type(8)));
typedef float  f32x4  __attribute__((ext_vector_type(4)));

#define LOG2E 1.44269504088896340736f

typedef __attribute__((address_space(1))) const void* as1cv;
typedef __attribute__((address_space(3))) void*       as3v;

__device__ __forceinline__ void gload16(const void* g, void* l) {
  __builtin_amdgcn_global_load_lds((as1cv)g, (as3v)l, 16, 0, 0);
}

__device__ __forceinline__ unsigned short f2b(float f) {
  union { float f; unsigned int u; } v; v.f = f;
  unsigned int r = v.u + 0x7fffu + ((v.u >> 16) & 1u);
  return (unsigned short)(r >> 16);
}

__device__ __forceinline__ float b2f(unsigned short s) {
  union { unsigned int u; float f; } v; v.u = (unsigned int)s << 16;
  return v.f;
}

// ---------------- dtype probe: bf16-interpret first 1024 u16 of x ----------------
// f32 data read as bf16 -> low halves have uniform exponents -> max explodes.
__global__ void detect_dtype(const unsigned short* __restrict__ x, int* __restrict__ flag) {
  const int t = threadIdx.x;  // 64
  bool big = false;
  for (int i = t; i < 1024; i += 64) {
    float f = b2f(x[i]);
    if (!(fabsf(f) < 1e6f)) big = true;  // catches inf/NaN/large
  }
  if (t == 0) *flag = 0;
  __syncthreads();
  if (__any(big) && t == 0) *flag = 1;
}

// ---------------- x -> bf16 copy/convert (8 elems/thread) ----------------
__global__ __launch_bounds__(256) void convert_x(const void* __restrict__ src,
                                                 unsigned short* __restrict__ dst,
                                                 const int* __restrict__ flag) {
  const int i = blockIdx.x * 256 + threadIdx.x;
  if (*flag) {
    float4 a = ((const float4*)src)[2 * i];
    float4 b = ((const float4*)src)[2 * i + 1];
    union { unsigned short o[8]; uint4 v; } u;
    u.o[0] = f2b(a.x); u.o[1] = f2b(a.y); u.o[2] = f2b(a.z); u.o[3] = f2b(a.w);
    u.o[4] = f2b(b.x); u.o[5] = f2b(b.y); u.o[6] = f2b(b.z); u.o[7] = f2b(b.w);
    ((uint4*)dst)[i] = u.v;
  } else {
    ((uint4*)dst)[i] = ((const uint4*)src)[i];
  }
}

// ---------------- weight transpose: src[R][C] (f32 or bf16) -> dst bf16 [C][R] ----------------
// grid (C/64, R/64), 256 threads
__global__ __launch_bounds__(256) void transpose_w(const void* __restrict__ src, int R, int C,
                                                   unsigned short* __restrict__ dst,
                                                   const int* __restrict__ flag) {
  __shared__ unsigned short tile[64][72];
  const int t = threadIdx.x;
  const int r = t >> 2;            // 0..63
  const int c0 = (t & 3) << 4;     // 0,16,32,48
  const int gr = blockIdx.y * 64 + r;
  const int gc = blockIdx.x * 64 + c0;
  if (*flag) {
    const float* s = (const float*)src + (size_t)gr * C + gc;
#pragma unroll
    for (int j = 0; j < 16; j += 4) {
      float4 v = *(const float4*)(s + j);
      tile[r][c0 + j + 0] = f2b(v.x);
      tile[r][c0 + j + 1] = f2b(v.y);
      tile[r][c0 + j + 2] = f2b(v.z);
      tile[r][c0 + j + 3] = f2b(v.w);
    }
  } else {
    const unsigned short* s = (const unsigned short*)src + (size_t)gr * C + gc;
    *(uint4*)&tile[r][c0]     = *(const uint4*)s;
    *(uint4*)&tile[r][c0 + 8] = *(const uint4*)(s + 8);
  }
  __syncthreads();
  const int c    = t >> 2;         // dst row within tile (= src col)
  const int rblk = (t & 3) << 4;   // dst col block (= src row)
  union { unsigned short o[16]; uint4 v[2]; } u;
#pragma unroll
  for (int j = 0; j < 16; ++j) u.o[j] = tile[rblk + j][c];
  unsigned short* d = dst + (size_t)(blockIdx.x * 64 + c) * R + blockIdx.y * 64 + rblk;
  *(uint4*)d       = u.v[0];
  *(uint4*)(d + 8) = u.v[1];
}

// ---------------- V transpose: QKV[b*S+s][2560+g*64+d] -> VT[(b*8+g)*64+d][s] ----------------
// grid: (S/64, 1, B*KVH), 256 threads
__global__ __launch_bounds__(256) void transpose_v(const unsigned short* __restrict__ qkv,
                                                   unsigned short* __restrict__ vt) {
  __shared__ unsigned short tile[64][72];
  const int t = threadIdx.x;
  const int r = t >> 2, c0 = (t & 3) << 4;
  const int z = blockIdx.z, b = z >> 3, g = z & 7;
  const unsigned short* s = qkv + (size_t)(b * 2048 + blockIdx.x * 64 + r) * 3072 + 2560 + g * 64 + c0;
  *(uint4*)&tile[r][c0]     = *(const uint4*)s;
  *(uint4*)&tile[r][c0 + 8] = *(const uint4*)(s + 8);
  __syncthreads();
  const int c = t >> 2, rblk = (t & 3) << 4;
  union { unsigned short o[16]; uint4 v[2]; } u;
#pragma unroll
  for (int j = 0; j < 16; ++j) u.o[j] = tile[rblk + j][c];
  unsigned short* d = vt + (size_t)(z * 64 + c) * 2048 + blockIdx.x * 64 + rblk;
  *(uint4*)d       = u.v[0];
  *(uint4*)(d + 8) = u.v[1];
}

// ---------------- m97-style bf16 GEMM: C[M][N] = A[M][K] @ Bt[N][K]^T ----------------
// grid: (N/128, M/128), 256 threads (4 waves, 2x2, each 64x64)
// f32flag: null -> bf16 output; else *f32flag selects f32 vs bf16 output store.
__global__ __launch_bounds__(256) void gemm_bt(const unsigned short* __restrict__ A,
                                               const unsigned short* __restrict__ Bt,
                                               void* __restrict__ Cv,
                                               int M, int N, int K,
                                               const int* __restrict__ f32flag) {
  __shared__ unsigned short As[128 * 32];
  __shared__ unsigned short Bs[128 * 32];
  const int t = threadIdx.x;
  const int lane = t & 63;
  const int wave = t >> 6;
  const int wm = wave >> 1, wn = wave & 1;
  const int m0 = blockIdx.y * 128, n0 = blockIdx.x * 128;
  const unsigned short* Ab = A + (size_t)m0 * K;
  const unsigned short* Bb = Bt + (size_t)n0 * K;
  const int fr = lane & 15;
  const int kb2 = (lane >> 4) << 4;  // frag k byte offset (16B per group)
  f32x4 acc[4][4] = {};
  for (int k0 = 0; k0 < K; k0 += 32) {
#pragma unroll
    for (int i = 0; i < 2; ++i) {
      int off = i * 4096 + t * 16;   // byte offset in 8KB tile
      int row = off >> 6;
      int cb  = off & 63;
      gload16(Ab + (size_t)row * K + k0 + (cb >> 1), (char*)As + off);
      gload16(Bb + (size_t)row * K + k0 + (cb >> 1), (char*)Bs + off);
    }
    __syncthreads();
    bf16x8 af[4], bfv[4];
#pragma unroll
    for (int i = 0; i < 4; ++i) {
      af[i]  = *(const bf16x8*)((const char*)As + (wm * 64 + i * 16 + fr) * 64 + kb2);
      bfv[i] = *(const bf16x8*)((const char*)Bs + (wn * 64 + i * 16 + fr) * 64 + kb2);
    }
#pragma unroll
    for (int i = 0; i < 4; ++i)
#pragma unroll
      for (int j = 0; j < 4; ++j)
        acc[i][j] = __builtin_amdgcn_mfma_f32_16x16x32_bf16(af[i], bfv[j], acc[i][j], 0, 0, 0);
    __syncthreads();
  }
  const int cm0 = m0 + wm * 64 + ((lane >> 4) << 2);
  const int cn0 = n0 + wn * 64 + fr;
  const bool of32 = f32flag && (*f32flag != 0);
  if (of32) {
    float* C = (float*)Cv;
#pragma unroll
    for (int i = 0; i < 4; ++i)
#pragma unroll
      for (int j = 0; j < 4; ++j)
#pragma unroll
        for (int r = 0; r < 4; ++r)
          C[(size_t)(cm0 + i * 16 + r) * N + (cn0 + j * 16)] = acc[i][j][r];
  } else {
    unsigned short* C = (unsigned short*)Cv;
#pragma unroll
    for (int i = 0; i < 4; ++i)
#pragma unroll
      for (int j = 0; j < 4; ++j)
#pragma unroll
        for (int r = 0; r < 4; ++r)
          C[(size_t)(cm0 + i * 16 + r) * N + (cn0 + j * 16)] = f2b(acc[i][j][r]);
  }
}

// ---------------- causal GQA flash attention ----------------
// grid: (S/64, H, B), 256 threads (4 waves, each owns 16 q-rows)
__global__ __launch_bounds__(256) void attn_fwd(const unsigned short* __restrict__ qkv,
                                                const unsigned short* __restrict__ vt,
                                                unsigned short* __restrict__ ob) {
  __shared__ unsigned short Qs[64 * 64];
  __shared__ unsigned short Ks[64 * 64];
  __shared__ unsigned short Vs[64 * 64];
  __shared__ unsigned short Ps[4 * 16 * 64];
  const int t = threadIdx.x;
  const int lane = t & 63;
  const int w = t >> 6;
  const int qt = blockIdx.x;
  const int h  = blockIdx.y;
  const int b  = blockIdx.z;
  const int g  = h >> 2;
  const size_t bS = (size_t)b * 2048;
  const int fr = lane & 15;
  const int fg = lane >> 4;

  // stage Q tile (pre-swizzled source -> linear LDS, XOR-swizzled layout)
#pragma unroll
  for (int i = 0; i < 2; ++i) {
    int off = i * 4096 + t * 16;
    int row = off >> 7;
    int cb  = (off & 127) ^ ((row & 7) << 4);
    gload16(qkv + (bS + qt * 64 + row) * 3072 + h * 64 + (cb >> 1), (char*)Qs + off);
  }
  __syncthreads();
  bf16x8 qf[2];
  {
    int row = w * 16 + fr;
    int sw = (row & 7) << 4;
#pragma unroll
    for (int kc = 0; kc < 2; ++kc)
      qf[kc] = *(const bf16x8*)((const char*)Qs + row * 128 + ((kc * 64 + (fg << 4)) ^ sw));
  }
  f32x4 O[4] = {};
  float mrow[4], lrow[4];
#pragma unroll
  for (int r = 0; r < 4; ++r) { mrow[r] = -1e30f; lrow[r] = 0.f; }
  const int q0 = qt * 64 + w * 16 + (fg << 2);  // +r = this lane/reg's global q row

  for (int kt = 0; kt <= qt; ++kt) {
    // stage K tile and V^T tile
#pragma unroll
    for (int i = 0; i < 2; ++i) {
      int off = i * 4096 + t * 16;
      int row = off >> 7;
      int cb  = (off & 127) ^ ((row & 7) << 4);
      gload16(qkv + (bS + kt * 64 + row) * 3072 + 2048 + g * 64 + (cb >> 1), (char*)Ks + off);
      gload16(vt + ((size_t)((b << 3) + g) * 64 + row) * 2048 + kt * 64 + (cb >> 1), (char*)Vs + off);
    }
    __syncthreads();
    // S = Q K^T
    f32x4 sc[4] = {};
#pragma unroll
    for (int nf = 0; nf < 4; ++nf) {
      int krow = nf * 16 + fr;
      int sw = (krow & 7) << 4;
#pragma unroll
      for (int kc = 0; kc < 2; ++kc) {
        bf16x8 kf = *(const bf16x8*)((const char*)Ks + krow * 128 + ((kc * 64 + (fg << 4)) ^ sw));
        sc[nf] = __builtin_amdgcn_mfma_f32_16x16x32_bf16(qf[kc], kf, sc[nf], 0, 0, 0);
      }
    }
    // scale + causal mask
    float sv[4][4];
    float pm[4];
#pragma unroll
    for (int r = 0; r < 4; ++r) pm[r] = -1e30f;
    const bool diag = (kt == qt);
#pragma unroll
    for (int nf = 0; nf < 4; ++nf) {
      int key = kt * 64 + nf * 16 + fr;
#pragma unroll
      for (int r = 0; r < 4; ++r) {
        float v = sc[nf][r] * 0.125f;
        if (diag && key > q0 + r) v = -1e30f;
        sv[nf][r] = v;
        pm[r] = fmaxf(pm[r], v);
      }
    }
#pragma unroll
    for (int d = 1; d < 16; d <<= 1)
#pragma unroll
      for (int r = 0; r < 4; ++r)
        pm[r] = fmaxf(pm[r], __shfl_xor(pm[r], d, 64));
    float rs[4];
#pragma unroll
    for (int r = 0; r < 4; ++r) {
      float mn = fmaxf(mrow[r], pm[r]);
      float scale = exp2f((mrow[r] - mn) * LOG2E);
      mrow[r] = mn;
      lrow[r] *= scale;
      rs[r] = 0.f;
#pragma unroll
      for (int df = 0; df < 4; ++df) O[df][r] *= scale;
    }
    // P -> per-wave LDS region (swizzled rows)
    char* Pw = (char*)Ps + w * 2048;
#pragma unroll
    for (int nf = 0; nf < 4; ++nf)
#pragma unroll
      for (int r = 0; r < 4; ++r) {
        float p = exp2f((sv[nf][r] - mrow[r]) * LOG2E);
        rs[r] += p;
        int qloc = (fg << 2) + r;
        int byteo = qloc * 128 + ((((nf * 16 + fr) * 2)) ^ ((qloc & 7) << 4));
        *(unsigned short*)(Pw + byteo) = f2b(p);
      }
#pragma unroll
    for (int d = 1; d < 16; d <<= 1)
#pragma unroll
      for (int r = 0; r < 4; ++r)
        rs[r] += __shfl_xor(rs[r], d, 64);
#pragma unroll
    for (int r = 0; r < 4; ++r) lrow[r] += rs[r];
    // O += P @ V
    {
      int psw = (fr & 7) << 4;
#pragma unroll
      for (int kc = 0; kc < 2; ++kc) {
        bf16x8 pf = *(const bf16x8*)((const char*)Pw + fr * 128 + ((kc * 64 + (fg << 4)) ^ psw));
#pragma unroll
        for (int df = 0; df < 4; ++df) {
          int vrow = df * 16 + fr;
          int vsw = (vrow & 7) << 4;
          bf16x8 vf = *(const bf16x8*)((const char*)Vs + vrow * 128 + ((kc * 64 + (fg << 4)) ^ vsw));
          O[df] = __builtin_amdgcn_mfma_f32_16x16x32_bf16(pf, vf, O[df], 0, 0, 0);
        }
      }
    }
    __syncthreads();
  }
  // epilogue
#pragma unroll
  for (int r = 0; r < 4; ++r) {
    float inv = 1.f / lrow[r];
    size_t orow = bS + (size_t)q0 + r;
#pragma unroll
    for (int df = 0; df < 4; ++df)
      ob[orow * 2048 + h * 64 + df * 16 + fr] = f2b(O[df][r] * inv);
  }
}

extern "C" void kernel_launch(void* const* d_in, const int* in_sizes, int n_in,
                              void* d_out, int out_size, void* d_ws, size_t ws_size,
                              hipStream_t stream) {
  (void)in_sizes; (void)n_in; (void)out_size; (void)ws_size;
  const void* x  = d_in[0];
  const void* wq = d_in[1];
  const void* wk = d_in[2];
  const void* wv = d_in[3];
  const void* wo = d_in[4];
  unsigned short* ws = (unsigned short*)d_ws;

  int* FLAG = (int*)ws;                                      // 128 u16 slot
  unsigned short* WT  = ws + 128;                            // [3072][2048]
  unsigned short* WOT = WT  + (size_t)3072 * 2048;           // [2048][2048]
  unsigned short* QKV = WOT + (size_t)2048 * 2048;           // [4096][3072]
  unsigned short* VT  = QKV + (size_t)4096 * 3072;           // [16*64][2048]
  unsigned short* OB  = VT  + (size_t)16 * 64 * 2048;        // [4096][2048]; also XB
  unsigned short* XB  = OB;                                  // x-as-bf16 (disjoint lifetime)

  detect_dtype<<<1, 64, 0, stream>>>((const unsigned short*)x, FLAG);

  transpose_w<<<dim3(32, 32), 256, 0, stream>>>(wq, 2048, 2048, WT, FLAG);
  transpose_w<<<dim3(8, 32), 256, 0, stream>>>(wk, 2048, 512, WT + (size_t)2048 * 2048, FLAG);
  transpose_w<<<dim3(8, 32), 256, 0, stream>>>(wv, 2048, 512, WT + (size_t)2560 * 2048, FLAG);
  transpose_w<<<dim3(32, 32), 256, 0, stream>>>(wo, 2048, 2048, WOT, FLAG);
  convert_x<<<4096, 256, 0, stream>>>(x, XB, FLAG);

  gemm_bt<<<dim3(24, 32), 256, 0, stream>>>(XB, WT, QKV, 4096, 3072, 2048, nullptr);
  transpose_v<<<dim3(32, 1, 16), 256, 0, stream>>>(QKV, VT);
  attn_fwd<<<dim3(32, 32, 2), 256, 0, stream>>>(QKV, VT, OB);
  gemm_bt<<<dim3(16, 32), 256, 0, stream>>>(OB, WOT, d_out, 4096, 2048, 2048, FLAG);
}

// Round 3
// 313.486 us; speedup vs baseline: 1.2976x; 1.2976x over previous
//
#include <hip/hip_runtime.h>
#include <stdint.h>

typedef __bf16 bf16x8 __attribute__((ext_vector_type(8)));
typedef float  f32x4  __attribute__((ext_vector_type(4)));
typedef float  f32x16 __attribute__((ext_vector_type(16)));

#define LOG2E 1.44269504088896340736f
#define QSCALE 0.18033688011112042f  /* 0.125 * log2(e) */

typedef __attribute__((address_space(1))) const void* as1cv;
typedef __attribute__((address_space(3))) void*       as3v;

__device__ __forceinline__ void gload16(const void* g, void* l) {
  __builtin_amdgcn_global_load_lds((as1cv)g, (as3v)l, 16, 0, 0);
}

__device__ __forceinline__ unsigned short f2b(float f) {
  union { float f; unsigned int u; } v; v.f = f;
  unsigned int r = v.u + 0x7fffu + ((v.u >> 16) & 1u);
  return (unsigned short)(r >> 16);
}

__device__ __forceinline__ float b2f(unsigned short s) {
  union { unsigned int u; float f; } v; v.u = (unsigned int)s << 16;
  return v.f;
}

// ---------------- dtype probe ----------------
__global__ void detect_dtype(const unsigned short* __restrict__ x, int* __restrict__ flag) {
  const int t = threadIdx.x;  // 64
  bool big = false;
  for (int i = t; i < 1024; i += 64) {
    float f = b2f(x[i]);
    if (!(fabsf(f) < 1e6f)) big = true;
  }
  if (t == 0) *flag = 0;
  __syncthreads();
  if (__any(big) && t == 0) *flag = 1;
}

// ---------------- x -> bf16 copy/convert ----------------
__global__ __launch_bounds__(256) void convert_x(const void* __restrict__ src,
                                                 unsigned short* __restrict__ dst,
                                                 const int* __restrict__ flag) {
  const int i = blockIdx.x * 256 + threadIdx.x;
  if (*flag) {
    float4 a = ((const float4*)src)[2 * i];
    float4 b = ((const float4*)src)[2 * i + 1];
    union { unsigned short o[8]; uint4 v; } u;
    u.o[0] = f2b(a.x); u.o[1] = f2b(a.y); u.o[2] = f2b(a.z); u.o[3] = f2b(a.w);
    u.o[4] = f2b(b.x); u.o[5] = f2b(b.y); u.o[6] = f2b(b.z); u.o[7] = f2b(b.w);
    ((uint4*)dst)[i] = u.v;
  } else {
    ((uint4*)dst)[i] = ((const uint4*)src)[i];
  }
}

// ---------------- weight transpose ----------------
__global__ __launch_bounds__(256) void transpose_w(const void* __restrict__ src, int R, int C,
                                                   unsigned short* __restrict__ dst,
                                                   const int* __restrict__ flag) {
  __shared__ unsigned short tile[64][72];
  const int t = threadIdx.x;
  const int r = t >> 2;
  const int c0 = (t & 3) << 4;
  const int gr = blockIdx.y * 64 + r;
  const int gc = blockIdx.x * 64 + c0;
  if (*flag) {
    const float* s = (const float*)src + (size_t)gr * C + gc;
#pragma unroll
    for (int j = 0; j < 16; j += 4) {
      float4 v = *(const float4*)(s + j);
      tile[r][c0 + j + 0] = f2b(v.x);
      tile[r][c0 + j + 1] = f2b(v.y);
      tile[r][c0 + j + 2] = f2b(v.z);
      tile[r][c0 + j + 3] = f2b(v.w);
    }
  } else {
    const unsigned short* s = (const unsigned short*)src + (size_t)gr * C + gc;
    *(uint4*)&tile[r][c0]     = *(const uint4*)s;
    *(uint4*)&tile[r][c0 + 8] = *(const uint4*)(s + 8);
  }
  __syncthreads();
  const int c    = t >> 2;
  const int rblk = (t & 3) << 4;
  union { unsigned short o[16]; uint4 v[2]; } u;
#pragma unroll
  for (int j = 0; j < 16; ++j) u.o[j] = tile[rblk + j][c];
  unsigned short* d = dst + (size_t)(blockIdx.x * 64 + c) * R + blockIdx.y * 64 + rblk;
  *(uint4*)d       = u.v[0];
  *(uint4*)(d + 8) = u.v[1];
}

// ---------------- V transpose: QKV[b*S+s][2560+g*64+d] -> VT[(b*8+g)*64+d][s] ----------------
__global__ __launch_bounds__(256) void transpose_v(const unsigned short* __restrict__ qkv,
                                                   unsigned short* __restrict__ vt) {
  __shared__ unsigned short tile[64][72];
  const int t = threadIdx.x;
  const int r = t >> 2, c0 = (t & 3) << 4;
  const int z = blockIdx.z, b = z >> 3, g = z & 7;
  const unsigned short* s = qkv + (size_t)(b * 2048 + blockIdx.x * 64 + r) * 3072 + 2560 + g * 64 + c0;
  *(uint4*)&tile[r][c0]     = *(const uint4*)s;
  *(uint4*)&tile[r][c0 + 8] = *(const uint4*)(s + 8);
  __syncthreads();
  const int c = t >> 2, rblk = (t & 3) << 4;
  union { unsigned short o[16]; uint4 v[2]; } u;
#pragma unroll
  for (int j = 0; j < 16; ++j) u.o[j] = tile[rblk + j][c];
  unsigned short* d = vt + (size_t)(z * 64 + c) * 2048 + blockIdx.x * 64 + rblk;
  *(uint4*)d       = u.v[0];
  *(uint4*)(d + 8) = u.v[1];
}

// ---------------- bf16 GEMM: C[M][N] = A[M][K] @ Bt[N][K]^T ----------------
// scale_cols: output cols < scale_cols are multiplied by QSCALE (Q pre-scaling).
__global__ __launch_bounds__(256) void gemm_bt(const unsigned short* __restrict__ A,
                                               const unsigned short* __restrict__ Bt,
                                               void* __restrict__ Cv,
                                               int M, int N, int K, int scale_cols,
                                               const int* __restrict__ f32flag) {
  __shared__ unsigned short As[128 * 32];
  __shared__ unsigned short Bs[128 * 32];
  const int t = threadIdx.x;
  const int lane = t & 63;
  const int wave = t >> 6;
  const int wm = wave >> 1, wn = wave & 1;
  const int m0 = blockIdx.y * 128, n0 = blockIdx.x * 128;
  const unsigned short* Ab = A + (size_t)m0 * K;
  const unsigned short* Bb = Bt + (size_t)n0 * K;
  const int fr = lane & 15;
  const int kb2 = (lane >> 4) << 4;
  f32x4 acc[4][4] = {};
  for (int k0 = 0; k0 < K; k0 += 32) {
#pragma unroll
    for (int i = 0; i < 2; ++i) {
      int off = i * 4096 + t * 16;
      int row = off >> 6;
      int cb  = off & 63;
      gload16(Ab + (size_t)row * K + k0 + (cb >> 1), (char*)As + off);
      gload16(Bb + (size_t)row * K + k0 + (cb >> 1), (char*)Bs + off);
    }
    __syncthreads();
    bf16x8 af[4], bfv[4];
#pragma unroll
    for (int i = 0; i < 4; ++i) {
      af[i]  = *(const bf16x8*)((const char*)As + (wm * 64 + i * 16 + fr) * 64 + kb2);
      bfv[i] = *(const bf16x8*)((const char*)Bs + (wn * 64 + i * 16 + fr) * 64 + kb2);
    }
#pragma unroll
    for (int i = 0; i < 4; ++i)
#pragma unroll
      for (int j = 0; j < 4; ++j)
        acc[i][j] = __builtin_amdgcn_mfma_f32_16x16x32_bf16(af[i], bfv[j], acc[i][j], 0, 0, 0);
    __syncthreads();
  }
  const int cm0 = m0 + wm * 64 + ((lane >> 4) << 2);
  const int cn0 = n0 + wn * 64 + fr;
  const bool of32 = f32flag && (*f32flag != 0);
  if (of32) {
    float* C = (float*)Cv;
#pragma unroll
    for (int i = 0; i < 4; ++i)
#pragma unroll
      for (int j = 0; j < 4; ++j) {
        float sc = (cn0 + j * 16 < scale_cols) ? QSCALE : 1.0f;
#pragma unroll
        for (int r = 0; r < 4; ++r)
          C[(size_t)(cm0 + i * 16 + r) * N + (cn0 + j * 16)] = acc[i][j][r] * sc;
      }
  } else {
    unsigned short* C = (unsigned short*)Cv;
#pragma unroll
    for (int i = 0; i < 4; ++i)
#pragma unroll
      for (int j = 0; j < 4; ++j) {
        float sc = (cn0 + j * 16 < scale_cols) ? QSCALE : 1.0f;
#pragma unroll
        for (int r = 0; r < 4; ++r)
          C[(size_t)(cm0 + i * 16 + r) * N + (cn0 + j * 16)] = f2b(acc[i][j][r] * sc);
      }
  }
}

// ---------------- causal GQA flash attention, swapped-QK^T 32x32 structure ----------------
// grid: (S/128, H, B), qt = (S/128-1) - blockIdx.x (descending work)
// 4 waves; wave w owns q-rows [qt*128+w*32, +32). Lane: q = Q0w + (lane&31), half = lane>>5.
// S^T = mfma32x32x16(K, Q) -> lane holds 32 of 64 scores for its q (k split across lane pair).
// O^T = mfma32x32x16(V^T, P^T) -> lane holds 32 of 64 d-values for its q.
__global__ __launch_bounds__(256) void attn_fwd2(const unsigned short* __restrict__ qkv,
                                                 const unsigned short* __restrict__ vt,
                                                 unsigned short* __restrict__ ob) {
  __shared__ unsigned short Ks[2][64 * 64];
  __shared__ unsigned short Vb2[2][64 * 64];
  const int t = threadIdx.x, lane = t & 63, w = t >> 6;
  const int half = lane >> 5, q32 = lane & 31;
  const int qt = (int)(gridDim.x - 1 - blockIdx.x);
  const int h = blockIdx.y, b = blockIdx.z, g = h >> 2;
  const size_t bS = (size_t)b * 2048;
  const int Q0w = qt * 128 + w * 32;
  const int q_glob = Q0w + q32;
  const int nkv = 2 * qt + 2;
  const int ktmax_w = (Q0w + 31) >> 6;
  const size_t vtbase = ((size_t)((b << 3) + g)) * 64;

  // Q fragments straight from global (Q already pre-scaled by QSCALE in GEMM epilogue)
  bf16x8 qf[4];
  {
    const unsigned short* qrow = qkv + (bS + q_glob) * 3072 + h * 64 + half * 8;
#pragma unroll
    for (int c = 0; c < 4; ++c) qf[c] = *(const bf16x8*)(qrow + 16 * c);
  }

  f32x16 Ot0 = {}, Ot1 = {};
  float m_run = -1e30f, l_run = 0.f;

  // prologue: stage tile 0
  {
#pragma unroll
    for (int i = 0; i < 2; ++i) {
      int off = i * 4096 + t * 16;
      int row = off >> 7;
      int cb  = (off & 127) ^ ((row & 7) << 4);
      gload16(qkv + (bS + row) * 3072 + 2048 + g * 64 + (cb >> 1), (char*)Ks[0] + off);
      gload16(vt + (vtbase + row) * 2048 + (cb >> 1), (char*)Vb2[0] + off);
    }
  }
  int cur = 0;
  for (int kt = 0; kt < nkv; ++kt) {
    __syncthreads();  // staging of buf[cur] complete (vmcnt drained) + prior reads done
    if (kt + 1 < nkv) {
      const int K1 = (kt + 1) * 64;
#pragma unroll
      for (int i = 0; i < 2; ++i) {
        int off = i * 4096 + t * 16;
        int row = off >> 7;
        int cb  = (off & 127) ^ ((row & 7) << 4);
        gload16(qkv + (bS + K1 + row) * 3072 + 2048 + g * 64 + (cb >> 1), (char*)Ks[cur ^ 1] + off);
        gload16(vt + (vtbase + row) * 2048 + K1 + (cb >> 1), (char*)Vb2[cur ^ 1] + off);
      }
    }
    if (kt <= ktmax_w) {
      const int K0 = kt * 64;
      // ---- S^T = K @ Q^T (per 32-key subtile) ----
      f32x16 s0 = {}, s1 = {};
      const char* Kb = (const char*)Ks[cur];
#pragma unroll
      for (int c = 0; c < 4; ++c) {
        int kr0 = q32;
        bf16x8 kf0 = *(const bf16x8*)(Kb + kr0 * 128 + (((2 * c + half) * 16) ^ ((kr0 & 7) << 4)));
        s0 = __builtin_amdgcn_mfma_f32_32x32x16_bf16(kf0, qf[c], s0, 0, 0, 0);
        int kr1 = 32 + q32;
        bf16x8 kf1 = *(const bf16x8*)(Kb + kr1 * 128 + (((2 * c + half) * 16) ^ ((kr1 & 7) << 4)));
        s1 = __builtin_amdgcn_mfma_f32_32x32x16_bf16(kf1, qf[c], s1, 0, 0, 0);
      }
      // ---- causal mask (only near-diagonal tiles) ----
      if (K0 + 63 > Q0w) {
        const int qrel = q_glob - K0 - 4 * half;
#pragma unroll
        for (int r = 0; r < 16; ++r) {
          const int pat = (r & 3) + 8 * (r >> 2);
          if (pat > qrel)      s0[r] = -1e30f;
          if (32 + pat > qrel) s1[r] = -1e30f;
        }
      }
      // ---- online softmax (lane-local + one pair-merge shfl) ----
      float pm = s0[0];
#pragma unroll
      for (int r = 1; r < 16; ++r) pm = fmaxf(pm, s0[r]);
#pragma unroll
      for (int r = 0; r < 16; ++r) pm = fmaxf(pm, s1[r]);
      pm = fmaxf(pm, __shfl_xor(pm, 32, 64));
      const float mn = fmaxf(m_run, pm);
      const float corr = exp2f(m_run - mn);
      m_run = mn;
      float rs = 0.f;
#pragma unroll
      for (int r = 0; r < 16; ++r) { float p = exp2f(s0[r] - m_run); s0[r] = p; rs += p; }
#pragma unroll
      for (int r = 0; r < 16; ++r) { float p = exp2f(s1[r] - m_run); s1[r] = p; rs += p; }
      rs += __shfl_xor(rs, 32, 64);
      l_run = l_run * corr + rs;
#pragma unroll
      for (int r = 0; r < 16; ++r) { Ot0[r] *= corr; Ot1[r] *= corr; }
      // ---- P (f32, lane-local) -> bf16 A-frags via cvt_pk + permlane32_swap ----
      bf16x8 pf[4];
#pragma unroll
      for (int st = 0; st < 2; ++st) {
#pragma unroll
        for (int cc = 0; cc < 2; ++cc) {
          unsigned int a01, a23, a45, a67;
          if (st == 0) {
            const int bse = cc * 8;
            asm("v_cvt_pk_bf16_f32 %0, %1, %2" : "=v"(a01) : "v"(s0[bse + 0]), "v"(s0[bse + 1]));
            asm("v_cvt_pk_bf16_f32 %0, %1, %2" : "=v"(a23) : "v"(s0[bse + 2]), "v"(s0[bse + 3]));
            asm("v_cvt_pk_bf16_f32 %0, %1, %2" : "=v"(a45) : "v"(s0[bse + 4]), "v"(s0[bse + 5]));
            asm("v_cvt_pk_bf16_f32 %0, %1, %2" : "=v"(a67) : "v"(s0[bse + 6]), "v"(s0[bse + 7]));
          } else {
            const int bse = cc * 8;
            asm("v_cvt_pk_bf16_f32 %0, %1, %2" : "=v"(a01) : "v"(s1[bse + 0]), "v"(s1[bse + 1]));
            asm("v_cvt_pk_bf16_f32 %0, %1, %2" : "=v"(a23) : "v"(s1[bse + 2]), "v"(s1[bse + 3]));
            asm("v_cvt_pk_bf16_f32 %0, %1, %2" : "=v"(a45) : "v"(s1[bse + 4]), "v"(s1[bse + 5]));
            asm("v_cvt_pk_bf16_f32 %0, %1, %2" : "=v"(a67) : "v"(s1[bse + 6]), "v"(s1[bse + 7]));
          }
          asm("v_permlane32_swap_b32 %0, %1" : "+v"(a01), "+v"(a45));
          asm("v_permlane32_swap_b32 %0, %1" : "+v"(a23), "+v"(a67));
          union { unsigned int u[4]; bf16x8 v; } fu;
          fu.u[0] = a01; fu.u[1] = a23; fu.u[2] = a45; fu.u[3] = a67;
          pf[st * 2 + cc] = fu.v;
        }
      }
      // ---- O^T += V^T @ P^T ----
      const char* Vbb = (const char*)Vb2[cur];
#pragma unroll
      for (int c = 0; c < 4; ++c) {
        int dr0 = q32;
        bf16x8 vf0 = *(const bf16x8*)(Vbb + dr0 * 128 + (((2 * c + half) * 16) ^ ((dr0 & 7) << 4)));
        Ot0 = __builtin_amdgcn_mfma_f32_32x32x16_bf16(vf0, pf[c], Ot0, 0, 0, 0);
        int dr1 = 32 + q32;
        bf16x8 vf1 = *(const bf16x8*)(Vbb + dr1 * 128 + (((2 * c + half) * 16) ^ ((dr1 & 7) << 4)));
        Ot1 = __builtin_amdgcn_mfma_f32_32x32x16_bf16(vf1, pf[c], Ot1, 0, 0, 0);
      }
    }
    cur ^= 1;
  }
  // ---- epilogue: O^T regs -> ob[q][h*64+d] ----
  const float inv = 1.f / l_run;
  unsigned short* orow = ob + (bS + q_glob) * 2048 + h * 64;
#pragma unroll
  for (int j = 0; j < 4; ++j) {
    uint2 pr;
    pr.x = (unsigned int)f2b(Ot0[4 * j + 0] * inv) | ((unsigned int)f2b(Ot0[4 * j + 1] * inv) << 16);
    pr.y = (unsigned int)f2b(Ot0[4 * j + 2] * inv) | ((unsigned int)f2b(Ot0[4 * j + 3] * inv) << 16);
    *(uint2*)(orow + 8 * j + 4 * half) = pr;
    uint2 pr2;
    pr2.x = (unsigned int)f2b(Ot1[4 * j + 0] * inv) | ((unsigned int)f2b(Ot1[4 * j + 1] * inv) << 16);
    pr2.y = (unsigned int)f2b(Ot1[4 * j + 2] * inv) | ((unsigned int)f2b(Ot1[4 * j + 3] * inv) << 16);
    *(uint2*)(orow + 32 + 8 * j + 4 * half) = pr2;
  }
}

extern "C" void kernel_launch(void* const* d_in, const int* in_sizes, int n_in,
                              void* d_out, int out_size, void* d_ws, size_t ws_size,
                              hipStream_t stream) {
  (void)in_sizes; (void)n_in; (void)out_size; (void)ws_size;
  const void* x  = d_in[0];
  const void* wq = d_in[1];
  const void* wk = d_in[2];
  const void* wv = d_in[3];
  const void* wo = d_in[4];
  unsigned short* ws = (unsigned short*)d_ws;

  int* FLAG = (int*)ws;
  unsigned short* WT  = ws + 128;
  unsigned short* WOT = WT  + (size_t)3072 * 2048;
  unsigned short* QKV = WOT + (size_t)2048 * 2048;
  unsigned short* VT  = QKV + (size_t)4096 * 3072;
  unsigned short* OB  = VT  + (size_t)16 * 64 * 2048;
  unsigned short* XB  = OB;  // x-as-bf16 (disjoint lifetime vs OB)

  detect_dtype<<<1, 64, 0, stream>>>((const unsigned short*)x, FLAG);

  transpose_w<<<dim3(32, 32), 256, 0, stream>>>(wq, 2048, 2048, WT, FLAG);
  transpose_w<<<dim3(8, 32), 256, 0, stream>>>(wk, 2048, 512, WT + (size_t)2048 * 2048, FLAG);
  transpose_w<<<dim3(8, 32), 256, 0, stream>>>(wv, 2048, 512, WT + (size_t)2560 * 2048, FLAG);
  transpose_w<<<dim3(32, 32), 256, 0, stream>>>(wo, 2048, 2048, WOT, FLAG);
  convert_x<<<4096, 256, 0, stream>>>(x, XB, FLAG);

  gemm_bt<<<dim3(24, 32), 256, 0, stream>>>(XB, WT, QKV, 4096, 3072, 2048, 2048, nullptr);
  transpose_v<<<dim3(32, 1, 16), 256, 0, stream>>>(QKV, VT);
  attn_fwd2<<<dim3(16, 32, 2), 256, 0, stream>>>(QKV, VT, OB);
  gemm_bt<<<dim3(16, 32), 256, 0, stream>>>(OB, WOT, d_out, 4096, 2048, 2048, 0, FLAG);
}